// Round 9
// baseline (839.549 us; speedup 1.0000x reference)
//
#include <hip/hip_runtime.h>
#include <hip/hip_bf16.h>
#include <math.h>

#define NPTS 4096
#define KD   64
#define BR   64                       // rows per block: 2 rowgroups x 32 rows
#define BC   128                      // cols per tile; each wave owns a 64-col half
#define NSPLIT 4                      // column splits
#define NPART  8                      // NSPLIT x 2 col-halves -> partials per dir
#define CT   (NPTS / (BC * NSPLIT))   // 8 col tiles per block
#define NTHREADS 256
#define BLOG2 (-12.0f)                // -log2(4096)
#define LOG2E 1.4426950408889634f
#define LN2   0.6931471805599453f

typedef __bf16 bf16x8 __attribute__((ext_vector_type(8)));
typedef float  f32x4  __attribute__((ext_vector_type(4)));

// fast transcendentals: raw v_exp_f32 / v_log_f32 (base-2, <=1 ulp)
__device__ __forceinline__ float ex2(float x) {
#if __has_builtin(__builtin_amdgcn_exp2f)
  return __builtin_amdgcn_exp2f(x);
#else
  return exp2f(x);
#endif
}
__device__ __forceinline__ float lg2(float x) {
#if __has_builtin(__builtin_amdgcn_logf)
  return __builtin_amdgcn_logf(x);   // v_log_f32 = log2
#else
  return log2f(x);
#endif
}

struct FusedArgs {
  const unsigned short* X[4];   // bf16 row-major [NPTS][KD]
  const unsigned short* Y[4];
  const float* csq[4];    // 0.5*|y_j|^2 of col-side points of dir d
  const float* pmr[4];    // prev-pass partial max [NPART][NPTS], paired dir
  const float* psr[4];    // prev-pass partial sum, paired dir
  const float* potr[4];   // prev potential of col-side points (paired dir)
  float* potw[4];         // blended potential out (paired dir slot)
  float* pm;              // this pass: [4][NPART][NPTS] partial max (base-2)
  float* ps;              // this pass: [4][NPART][NPTS] partial sum
  float ie2;              // log2(e) / eps_cur
  float elp;              // eps_prev * ln(2)
  float alpha, beta;      // potential blend g = alpha*prev + beta*v
  int mode;               // 0 = init (g = 0, no partials), 1 = merge prev pass
};

// async 16B/lane global->LDS; lds dest = wave-uniform base + lane*16
__device__ __forceinline__ void gll16(const void* g, void* l) {
  __builtin_amdgcn_global_load_lds(
      (const __attribute__((address_space(1))) void*)g,
      (__attribute__((address_space(3))) void*)l, 16, 0, 0);
}

// One softmin pass, all 4 directions via blockIdx.z.
// ROUND-9 = round-7 (637us verified) + round-6's VERIFIED fragment-sharing
// wave map: wave -> (rowgrp = wave>>1, half = wave&1); each wave owns 2
// row-tiles (32 rows) x 4 col-tiles (64 cols) so each B ds_read_b128 feeds
// 2 MFMAs -> B LDS traffic halves. Each (split,half) writes its own partial
// (NPART=8). Round-6's regression was the allocator picking the 64-VGPR /
// 8-waves-per-EU bin and spilling ~17 dwords/thread (WRITE_SIZE 18 MB);
// amdgpu_waves_per_eu(4,4) pins the 4-waves/EU bin (<=128 VGPR, no spill).
// Y tile staged via global_load_lds, XOR seg swizzle: LDS 16B-seg p of col r
// holds global seg p^(r&7) -> conflict-free b128 reads, no padding.
__global__ __launch_bounds__(NTHREADS)
__attribute__((amdgpu_waves_per_eu(4, 4)))
void fused_softmin(FusedArgs A) {
  __shared__ __align__(16) __bf16 YT[2][BC * KD];   // 2 x 16 KB
  __shared__ __align__(16) float QL[BC * CT];       // 4 KB: this split's q

  const int tid  = threadIdx.x;
  const int lane = tid & 63;
  const int wave = tid >> 6;       // 0..3
  const int rowgrp = wave >> 1;    // 0..1 : 32-row group
  const int half   = wave & 1;     // 0..1 : 64-col half
  const int ln16 = lane & 15;      // A row / B,C col within 16
  const int rg   = lane >> 4;      // k-seg for A/B; row-quad for C
  const int ln7  = ln16 & 7;
  const int rowblk = blockIdx.x;
  const int split  = blockIdx.y;
  const int dir    = blockIdx.z;

  const __bf16* __restrict__ Xb = (const __bf16*)A.X[dir];
  const __bf16* __restrict__ Yb = (const __bf16*)A.Y[dir];
  const float ie2 = A.ie2;
  const int row0 = rowblk * BR;
  const int col0 = split * (CT * BC);

  // staging geometry: linear idx = it*256 + tid; col = idx>>3, seg = idx&7
  const int srow = tid >> 3;
  const int sseg = tid & 7;

  // issue tile-0 Y staging (async)
#pragma unroll
  for (int it = 0; it < 4; ++it) {
    int r = it * 32 + srow;
    gll16(Yb + (size_t)(col0 + r) * KD + ((sseg ^ (r & 7)) << 3),
          (__bf16*)YT[0] + it * 2048 + wave * 512);
  }

  // A fragments: global -> VGPR, once. af[rt][ks]
  bf16x8 af[2][2];
#pragma unroll
  for (int rt = 0; rt < 2; ++rt) {
    const __bf16* ap = Xb + (size_t)(row0 + rowgrp * 32 + rt * 16 + ln16) * KD + rg * 8;
#pragma unroll
    for (int ks = 0; ks < 2; ++ks) {
      union { uint4 u; bf16x8 v; } t;
      t.u = *(const uint4*)(ap + ks * 32);
      af[rt][ks] = t.v;
    }
  }

  // ---- fused merge prologue: build q for this split's 1024 cols ----
  {
    const float* __restrict__ csq = A.csq[dir];
    if (A.mode == 0) {
#pragma unroll
      for (int i = 0; i < 4; ++i) {
        int c = col0 + tid + i * 256;
        QL[tid + i * 256] = BLOG2 - csq[c] * ie2;     // g = 0
      }
    } else {
      const float* __restrict__ pmr = A.pmr[dir];
      const float* __restrict__ psr = A.psr[dir];
      const float* __restrict__ potr = A.potr[dir];
      float* __restrict__ potw = A.potw[dir];
#pragma unroll
      for (int i = 0; i < 4; ++i) {
        int c = col0 + tid + i * 256;
        float mv[NPART], sv[NPART];
        float m4 = -__builtin_inff();
#pragma unroll
        for (int sp = 0; sp < NPART; ++sp) {
          mv[sp] = pmr[sp * NPTS + c];
          sv[sp] = psr[sp * NPTS + c];
          m4 = fmaxf(m4, mv[sp]);
        }
        float s4 = 0.f;
#pragma unroll
        for (int sp = 0; sp < NPART; ++sp) s4 += sv[sp] * ex2(mv[sp] - m4);
        float lse2 = m4 + lg2(s4);
        float xsq = csq[c];
        float v = xsq - A.elp * lse2;                 // elp = eps_prev*ln2
        float g = A.alpha * potr[c] + A.beta * v;
        if (rowblk == 0) potw[c] = g;
        QL[tid + i * 256] = BLOG2 + (g - xsq) * ie2;
      }
    }
  }

  float m[2][4], s[2][4];
#pragma unroll
  for (int rt = 0; rt < 2; ++rt)
#pragma unroll
    for (int r = 0; r < 4; ++r) { m[rt][r] = -__builtin_inff(); s[rt][r] = 0.f; }

  __syncthreads();   // drains tile-0 staging; QL visible to all waves

  for (int tile = 0; tile < CT; ++tile) {
    const int cb = tile & 1;

    // async prefetch next tile (drained by end-of-tile barrier)
    if (tile < CT - 1) {
      const int nc0 = col0 + (tile + 1) * BC;
#pragma unroll
      for (int it = 0; it < 4; ++it) {
        int r = it * 32 + srow;
        gll16(Yb + (size_t)(nc0 + r) * KD + ((sseg ^ (r & 7)) << 3),
              (__bf16*)YT[cb ^ 1] + it * 2048 + wave * 512);
      }
    }

    float qv[4];
#pragma unroll
    for (int ct = 0; ct < 4; ++ct)
      qv[ct] = QL[tile * BC + half * 64 + ct * 16 + ln16];

    f32x4 acc[2][4] = {};

    const __bf16* yb0 = YT[cb] + (half * 64 + ln16) * KD;
#pragma unroll
    for (int ks = 0; ks < 2; ++ks) {
      const int p = ((ks << 2) | rg) ^ ln7;
#pragma unroll
      for (int ct = 0; ct < 4; ++ct) {
        union { uint4 u; bf16x8 v; } bb;
        bb.u = *(const uint4*)(yb0 + ct * 16 * KD + p * 8);
        acc[0][ct] = __builtin_amdgcn_mfma_f32_16x16x32_bf16(af[0][ks], bb.v, acc[0][ct], 0, 0, 0);
        acc[1][ct] = __builtin_amdgcn_mfma_f32_16x16x32_bf16(af[1][ks], bb.v, acc[1][ct], 0, 0, 0);
      }
    }

    // online-softmax epilogue (round-6 verified mapping, fast ex2)
#pragma unroll
    for (int rt = 0; rt < 2; ++rt)
#pragma unroll
      for (int r = 0; r < 4; ++r) {
        float l0 = fmaf(acc[rt][0][r], ie2, qv[0]);
        float l1 = fmaf(acc[rt][1][r], ie2, qv[1]);
        float l2 = fmaf(acc[rt][2][r], ie2, qv[2]);
        float l3 = fmaf(acc[rt][3][r], ie2, qv[3]);
        float mn = fmaxf(m[rt][r], fmaxf(fmaxf(l0, l1), fmaxf(l2, l3)));
        float sadd = ex2(l0 - mn) + ex2(l1 - mn) + ex2(l2 - mn) + ex2(l3 - mn);
        s[rt][r] = fmaf(s[rt][r], ex2(m[rt][r] - mn), sadd);
        m[rt][r] = mn;
      }
    __syncthreads();
  }

  // intra-wave merge over the 16 col-owner lanes (masks 1..8 keep rg)
#pragma unroll
  for (int rt = 0; rt < 2; ++rt)
#pragma unroll
    for (int r = 0; r < 4; ++r) {
#pragma unroll
      for (int d = 1; d < 16; d <<= 1) {
        float mo = __shfl_xor(m[rt][r], d, 64);
        float so = __shfl_xor(s[rt][r], d, 64);
        float mn = fmaxf(m[rt][r], mo);
        s[rt][r] = ex2(m[rt][r] - mn) * s[rt][r] + ex2(mo - mn) * so;
        m[rt][r] = mn;
      }
    }
  if (ln16 == 0) {
#pragma unroll
    for (int rt = 0; rt < 2; ++rt)
#pragma unroll
      for (int r = 0; r < 4; ++r) {
        int row = row0 + rowgrp * 32 + rt * 16 + rg * 4 + r;
        size_t gi = (size_t)(dir * NPART + split * 2 + half) * NPTS + row;
        A.pm[gi] = m[rt][r];
        A.ps[gi] = s[rt][r];
      }
  }
}

// sqnorms + bf16 conversion
__global__ void prep(const float* __restrict__ x, const float* __restrict__ y,
                     float* xs, float* ys,
                     unsigned short* xb, unsigned short* yb) {
  int gid = blockIdx.x * blockDim.x + threadIdx.x;  // 0..8191
  int isx = (gid < NPTS) ? 1 : 0;
  const float* p = isx ? x : y;
  int row = gid & (NPTS - 1);
  const float4* r4 = (const float4*)(p + (size_t)row * KD);
  unsigned short* ob = (isx ? xb : yb) + (size_t)row * KD;
  float s = 0.f;
#pragma unroll
  for (int i = 0; i < 16; ++i) {
    float4 v = r4[i];
    s += v.x * v.x + v.y * v.y + v.z * v.z + v.w * v.w;
    union { __bf16 h[4]; uint2 u; } t;
    t.h[0] = (__bf16)v.x; t.h[1] = (__bf16)v.y;
    t.h[2] = (__bf16)v.z; t.h[3] = (__bf16)v.w;
    *(uint2*)(ob + i * 4) = t.u;
  }
  (isx ? xs : ys)[row] = 0.5f * s;
}

// Merge the FINAL extrapolation pass's partials for all 4 dirs and reduce:
// out = (1/N) * sum_rows[(f0 - f2) + (f1 - f3)]
__global__ void final_reduce(const float* __restrict__ pm,
                             const float* __restrict__ ps,
                             const float* __restrict__ xsx,
                             const float* __restrict__ xsy,
                             float elpF, float* out) {
  __shared__ float red[256];
  int t = threadIdx.x;
  float acc = 0.f;
  for (int r = t; r < NPTS; r += 256) {
#pragma unroll
    for (int d = 0; d < 4; ++d) {
      float mv[NPART], sv[NPART];
      float m4 = -__builtin_inff();
#pragma unroll
      for (int sp = 0; sp < NPART; ++sp) {
        mv[sp] = pm[(size_t)(d * NPART + sp) * NPTS + r];
        sv[sp] = ps[(size_t)(d * NPART + sp) * NPTS + r];
        m4 = fmaxf(m4, mv[sp]);
      }
      float s4 = 0.f;
#pragma unroll
      for (int sp = 0; sp < NPART; ++sp) s4 += sv[sp] * ex2(mv[sp] - m4);
      float lse2 = m4 + lg2(s4);
      float xsq = (d == 0 || d == 2) ? xsx[r] : xsy[r];
      float f = xsq - elpF * lse2;
      acc += (d < 2) ? f : -f;
    }
  }
  red[t] = acc;
  __syncthreads();
  for (int off = 128; off > 0; off >>= 1) {
    if (t < off) red[t] += red[t + off];
    __syncthreads();
  }
  if (t == 0) out[0] = red[0] * (1.0f / NPTS);
}

extern "C" void kernel_launch(void* const* d_in, const int* in_sizes, int n_in,
                              void* d_out, int out_size, void* d_ws, size_t ws_size,
                              hipStream_t stream) {
  const float* x = (const float*)d_in[0];
  const float* y = (const float*)d_in[1];
  float* out = (float*)d_out;
  float* w = (float*)d_ws;

  // ws layout (float slots); total 202*NPTS ~ 3.3 MB
  float* xs_x = w;                         // [NPTS]
  float* xs_y = w + NPTS;                  // [NPTS]
  float* pot0 = w + 2 * NPTS;              // [4][NPTS] potential ping
  float* pot1 = w + 6 * NPTS;              // [4][NPTS] potential pong
  float* pm0  = w + 10 * NPTS;             // [4][NPART][NPTS]
  float* ps0  = w + 42 * NPTS;
  float* pm1  = w + 74 * NPTS;
  float* ps1  = w + 106 * NPTS;
  unsigned short* xb = (unsigned short*)(w + 138 * NPTS);  // [NPTS][KD] bf16
  unsigned short* yb = (unsigned short*)(w + 170 * NPTS);  // [NPTS][KD] bf16
  float* pmb[2] = {pm0, pm1};
  float* psb[2] = {ps0, ps1};
  float* potb[2] = {pot0, pot1};

  // geomloss epsilon_schedule(p=2, diameter=20, blur=0.01, scaling=0.7)
  double eps_list[32];
  int neps = 0;
  {
    double start = 2.0 * log(20.0);
    double stop  = 2.0 * log(0.01);
    double step  = 2.0 * log(0.7);
    eps_list[neps++] = 400.0;
    int cnt = (int)ceil((stop - start) / step);  // 22
    for (int i = 0; i < cnt && neps < 30; ++i) eps_list[neps++] = exp(start + (double)i * step);
    eps_list[neps++] = 1e-4;                     // neps == 24
  }

  // dir 0: ft (rows x, cols y); dir 1: gt (rows y, cols x)
  // dir 2: f_aa (x,x); dir 3: g_bb (y,y).  qpair = paired dir whose ROWS are
  // this dir's COLS: {1,0,2,3}.
  const unsigned short* Xd[4] = {xb, yb, xb, yb};
  const unsigned short* Yd[4] = {yb, xb, xb, yb};
  const float* YSQd[4] = {xs_y, xs_x, xs_x, xs_y};   // col-side sqnorms
  const int qpair[4] = {1, 0, 2, 3};

  prep<<<dim3(32), dim3(256), 0, stream>>>(x, y, xs_x, xs_y, xb, yb);

  dim3 fgrid(NPTS / BR, NSPLIT, 4);   // 64 x 4 x 4 = 1024 blocks = 4/CU

  // eps used by launch k (k = 0 init, 1..24 loop, 25 final extrapolation)
  double ecur[26];
  ecur[0] = eps_list[0];
  for (int k = 1; k <= 24; ++k) ecur[k] = eps_list[k - 1];
  ecur[25] = eps_list[neps - 1];

  for (int k = 0; k <= 25; ++k) {
    FusedArgs fa;
    for (int d = 0; d < 4; ++d) {
      fa.X[d] = Xd[d]; fa.Y[d] = Yd[d]; fa.csq[d] = YSQd[d];
      int p = qpair[d];
      fa.pmr[d]  = pmb[(k + 1) & 1] + (size_t)p * NPART * NPTS;
      fa.psr[d]  = psb[(k + 1) & 1] + (size_t)p * NPART * NPTS;
      fa.potr[d] = potb[(k + 1) & 1] + (size_t)p * NPTS;
      fa.potw[d] = potb[k & 1] + (size_t)p * NPTS;
    }
    fa.pm = pmb[k & 1];
    fa.ps = psb[k & 1];
    fa.ie2 = (float)(LOG2E / ecur[k]);
    fa.elp = (k == 0) ? 0.f : (float)(ecur[k - 1] * LN2);
    fa.alpha = (k <= 1) ? 0.f : 0.5f;
    fa.beta  = (k <= 1) ? 1.f : 0.5f;
    fa.mode  = (k == 0) ? 0 : 1;
    fused_softmin<<<fgrid, dim3(NTHREADS), 0, stream>>>(fa);
  }

  final_reduce<<<dim3(1), dim3(256), 0, stream>>>(
      pmb[25 & 1], psb[25 & 1], xs_x, xs_y,
      (float)(eps_list[neps - 1] * LN2), out);
}

// Round 10
// 634.234 us; speedup vs baseline: 1.3237x; 1.3237x over previous
//
#include <hip/hip_runtime.h>
#include <hip/hip_bf16.h>
#include <math.h>

#define NPTS 4096
#define KD   64
#define BR   64                       // rows per block (4 waves x 16 rows)
#define BC   128                      // cols per tile
#define NSPLIT 4                      // column splits (partial LSE per split)
#define CT   (NPTS / (BC * NSPLIT))   // 8 col tiles per block
#define NTHREADS 256
#define BLOG2 (-12.0f)                // -log2(4096)
#define LOG2E 1.4426950408889634f
#define LN2   0.6931471805599453f

typedef __bf16 bf16x8 __attribute__((ext_vector_type(8)));
typedef float  f32x4  __attribute__((ext_vector_type(4)));

// fast transcendentals: raw v_exp_f32 / v_log_f32 (base-2, <=1 ulp)
__device__ __forceinline__ float ex2(float x) {
#if __has_builtin(__builtin_amdgcn_exp2f)
  return __builtin_amdgcn_exp2f(x);
#else
  return exp2f(x);
#endif
}
__device__ __forceinline__ float lg2(float x) {
#if __has_builtin(__builtin_amdgcn_logf)
  return __builtin_amdgcn_logf(x);   // v_log_f32 = log2
#else
  return log2f(x);
#endif
}

struct FusedArgs {
  const unsigned short* X[4];   // bf16 row-major [NPTS][KD]
  const unsigned short* Y[4];
  const float* csq[4];    // 0.5*|y_j|^2 of col-side points of dir d
  const float* pmr[4];    // prev-pass partial max, paired dir
  const float* psr[4];    // prev-pass partial sum, paired dir
  const float* potr[4];   // prev potential of col-side points (paired dir)
  float* potw[4];         // blended potential out (paired dir slot)
  float* pm;              // this pass: [4][NSPLIT][NPTS] partial max (base-2)
  float* ps;              // this pass: [4][NSPLIT][NPTS] partial sum
  float ie2;              // log2(e) / eps_cur
  float elp;              // eps_prev * ln(2)
  float alpha, beta;      // potential blend g = alpha*prev + beta*v
  int mode;               // 0 = init (g = 0, no partials), 1 = merge prev pass
};

// async 16B/lane global->LDS; lds dest = wave-uniform base + lane*16
__device__ __forceinline__ void gll16(const void* g, void* l) {
  __builtin_amdgcn_global_load_lds(
      (const __attribute__((address_space(1))) void*)g,
      (__attribute__((address_space(3))) void*)l, 16, 0, 0);
}

// One softmin pass, all 4 directions via blockIdx.z — EXACT round-7 verified
// kernel (637 us config; 16x16x32 MFMA, each wave 16 rows x full 128-col
// tile, 4 blocks/CU). Fragment-sharing remaps (r6/r8/r9) all regressed:
// spill (r6), occupancy cliff (r8), prologue+remap overhead (r9). Keep this.
// Y tile staged via global_load_lds, XOR seg swizzle: LDS 16B-seg p of col r
// holds global seg p^(r&7) -> conflict-free b128 reads, no padding.
__global__ __launch_bounds__(NTHREADS, 4)
void fused_softmin(FusedArgs A) {
  __shared__ __align__(16) __bf16 YT[2][BC * KD];   // 2 x 16 KB
  __shared__ __align__(16) float QL[BC * CT];       // 4 KB: this split's q

  const int tid  = threadIdx.x;
  const int lane = tid & 63;
  const int wave = tid >> 6;
  const int ln16 = lane & 15;   // A row / B,C col within 16
  const int rg   = lane >> 4;   // k-seg for A/B; row-quad for C
  const int ln7  = ln16 & 7;
  const int rowblk = blockIdx.x;
  const int split  = blockIdx.y;
  const int dir    = blockIdx.z;

  const __bf16* __restrict__ Xb = (const __bf16*)A.X[dir];
  const __bf16* __restrict__ Yb = (const __bf16*)A.Y[dir];
  const float ie2 = A.ie2;
  const int row0 = rowblk * BR;
  const int col0 = split * (CT * BC);

  // staging geometry: linear idx = it*256 + tid; col = idx>>3, seg = idx&7
  const int srow = tid >> 3;
  const int sseg = tid & 7;

  // issue tile-0 Y staging (async)
#pragma unroll
  for (int it = 0; it < 4; ++it) {
    int r = it * 32 + srow;
    gll16(Yb + (size_t)(col0 + r) * KD + ((sseg ^ (r & 7)) << 3),
          (__bf16*)YT[0] + it * 2048 + wave * 512);
  }

  // A fragments: global -> VGPR, once
  bf16x8 af[2];
  {
    const __bf16* ap = Xb + (size_t)(row0 + wave * 16 + ln16) * KD + rg * 8;
#pragma unroll
    for (int ks = 0; ks < 2; ++ks) {
      union { uint4 u; bf16x8 v; } t;
      t.u = *(const uint4*)(ap + ks * 32);
      af[ks] = t.v;
    }
  }

  // ---- fused merge prologue: build q for this split's 1024 cols ----
  {
    const float* __restrict__ csq = A.csq[dir];
    if (A.mode == 0) {
#pragma unroll
      for (int i = 0; i < 4; ++i) {
        int c = col0 + tid + i * 256;
        QL[tid + i * 256] = BLOG2 - csq[c] * ie2;     // g = 0
      }
    } else {
      const float* __restrict__ pmr = A.pmr[dir];
      const float* __restrict__ psr = A.psr[dir];
      const float* __restrict__ potr = A.potr[dir];
      float* __restrict__ potw = A.potw[dir];
#pragma unroll
      for (int i = 0; i < 4; ++i) {
        int c = col0 + tid + i * 256;
        float m0 = pmr[0 * NPTS + c], m1 = pmr[1 * NPTS + c];
        float m2 = pmr[2 * NPTS + c], m3 = pmr[3 * NPTS + c];
        float s0 = psr[0 * NPTS + c], s1 = psr[1 * NPTS + c];
        float s2 = psr[2 * NPTS + c], s3 = psr[3 * NPTS + c];
        float m4 = fmaxf(fmaxf(m0, m1), fmaxf(m2, m3));
        float s4 = s0 * ex2(m0 - m4) + s1 * ex2(m1 - m4) +
                   s2 * ex2(m2 - m4) + s3 * ex2(m3 - m4);
        float lse2 = m4 + lg2(s4);
        float xsq = csq[c];
        float v = xsq - A.elp * lse2;                 // elp = eps_prev*ln2
        float g = A.alpha * potr[c] + A.beta * v;
        if (rowblk == 0) potw[c] = g;
        QL[tid + i * 256] = BLOG2 + (g - xsq) * ie2;
      }
    }
  }

  float m[4], s[4];
#pragma unroll
  for (int r = 0; r < 4; ++r) { m[r] = -__builtin_inff(); s[r] = 0.f; }

  __syncthreads();   // drains tile-0 staging; QL visible to all waves

  for (int tile = 0; tile < CT; ++tile) {
    const int cb = tile & 1;

    // async prefetch next tile (drained by end-of-tile barrier)
    if (tile < CT - 1) {
      const int nc0 = col0 + (tile + 1) * BC;
#pragma unroll
      for (int it = 0; it < 4; ++it) {
        int r = it * 32 + srow;
        gll16(Yb + (size_t)(nc0 + r) * KD + ((sseg ^ (r & 7)) << 3),
              (__bf16*)YT[cb ^ 1] + it * 2048 + wave * 512);
      }
    }

    float qv[8];
#pragma unroll
    for (int t = 0; t < 8; ++t) qv[t] = QL[tile * BC + t * 16 + ln16];

    f32x4 acc[8];
#pragma unroll
    for (int t = 0; t < 8; ++t)
#pragma unroll
      for (int i = 0; i < 4; ++i) acc[t][i] = 0.f;

    const __bf16* ybase = YT[cb] + ln16 * KD;
#pragma unroll
    for (int ks = 0; ks < 2; ++ks) {
      const int p = ((ks << 2) | rg) ^ ln7;
#pragma unroll
      for (int t = 0; t < 8; ++t) {
        union { uint4 u; bf16x8 v; } bb;
        bb.u = *(const uint4*)(ybase + t * 16 * KD + p * 8);
        acc[t] = __builtin_amdgcn_mfma_f32_16x16x32_bf16(af[ks], bb.v, acc[t], 0, 0, 0);
      }
    }

#pragma unroll
    for (int r = 0; r < 4; ++r) {
      float l[8];
#pragma unroll
      for (int t = 0; t < 8; ++t) l[t] = fmaf(acc[t][r], ie2, qv[t]);
      float tmax = -__builtin_inff();
#pragma unroll
      for (int t = 0; t < 8; ++t) tmax = fmaxf(tmax, l[t]);
      float mn = fmaxf(m[r], tmax);
      float sadd = 0.f;
#pragma unroll
      for (int t = 0; t < 8; ++t) sadd += ex2(l[t] - mn);
      s[r] = fmaf(s[r], ex2(m[r] - mn), sadd);
      m[r] = mn;
    }
    __syncthreads();
  }

  // cross-lane merge over the 16 col-owner lanes (masks 1..8 keep rg)
#pragma unroll
  for (int r = 0; r < 4; ++r) {
#pragma unroll
    for (int d = 1; d < 16; d <<= 1) {
      float mo = __shfl_xor(m[r], d, 64);
      float so = __shfl_xor(s[r], d, 64);
      float mn = fmaxf(m[r], mo);
      s[r] = ex2(m[r] - mn) * s[r] + ex2(mo - mn) * so;
      m[r] = mn;
    }
  }
  if (ln16 == 0) {
#pragma unroll
    for (int r = 0; r < 4; ++r) {
      int row = row0 + wave * 16 + rg * 4 + r;
      size_t gi = (size_t)(dir * NSPLIT + split) * NPTS + row;
      A.pm[gi] = m[r];
      A.ps[gi] = s[r];
    }
  }
}

// sqnorms + bf16 conversion
__global__ void prep(const float* __restrict__ x, const float* __restrict__ y,
                     float* xs, float* ys,
                     unsigned short* xb, unsigned short* yb) {
  int gid = blockIdx.x * blockDim.x + threadIdx.x;  // 0..8191
  int isx = (gid < NPTS) ? 1 : 0;
  const float* p = isx ? x : y;
  int row = gid & (NPTS - 1);
  const float4* r4 = (const float4*)(p + (size_t)row * KD);
  unsigned short* ob = (isx ? xb : yb) + (size_t)row * KD;
  float s = 0.f;
#pragma unroll
  for (int i = 0; i < 16; ++i) {
    float4 v = r4[i];
    s += v.x * v.x + v.y * v.y + v.z * v.z + v.w * v.w;
    union { __bf16 h[4]; uint2 u; } t;
    t.h[0] = (__bf16)v.x; t.h[1] = (__bf16)v.y;
    t.h[2] = (__bf16)v.z; t.h[3] = (__bf16)v.w;
    *(uint2*)(ob + i * 4) = t.u;
  }
  (isx ? xs : ys)[row] = 0.5f * s;
}

// ROUND-10: two-stage final reduction. The old single-block final_reduce was
// an 88 us latency-bound tail (0.04% occupancy, 6 GB/s). Stage 1 spreads the
// 512 KB partial-merge over 64 blocks; stage 2 sums 64 floats in one wave.
__global__ void final_partial(const float* __restrict__ pm,
                              const float* __restrict__ ps,
                              const float* __restrict__ xsx,
                              const float* __restrict__ xsy,
                              float elpF, float* blkout) {
  __shared__ float red[256];
  int t = threadIdx.x;
  int gid = blockIdx.x * 256 + t;        // 0..16383 = (dir, row)
  int d = gid >> 12;
  int r = gid & (NPTS - 1);
  float m0 = pm[(size_t)(d * NSPLIT + 0) * NPTS + r];
  float m1 = pm[(size_t)(d * NSPLIT + 1) * NPTS + r];
  float m2 = pm[(size_t)(d * NSPLIT + 2) * NPTS + r];
  float m3 = pm[(size_t)(d * NSPLIT + 3) * NPTS + r];
  float s0 = ps[(size_t)(d * NSPLIT + 0) * NPTS + r];
  float s1 = ps[(size_t)(d * NSPLIT + 1) * NPTS + r];
  float s2 = ps[(size_t)(d * NSPLIT + 2) * NPTS + r];
  float s3 = ps[(size_t)(d * NSPLIT + 3) * NPTS + r];
  float m4 = fmaxf(fmaxf(m0, m1), fmaxf(m2, m3));
  float s4 = s0 * ex2(m0 - m4) + s1 * ex2(m1 - m4) +
             s2 * ex2(m2 - m4) + s3 * ex2(m3 - m4);
  float lse2 = m4 + lg2(s4);
  float xsq = (d == 0 || d == 2) ? xsx[r] : xsy[r];
  float f = xsq - elpF * lse2;
  red[t] = (d < 2) ? f : -f;
  __syncthreads();
  for (int off = 128; off > 0; off >>= 1) {
    if (t < off) red[t] += red[t + off];
    __syncthreads();
  }
  if (t == 0) blkout[blockIdx.x] = red[0];
}

__global__ void final_sum(const float* __restrict__ blkin, float* out) {
  int t = threadIdx.x;   // 64 threads = 1 wave
  float v = blkin[t];
#pragma unroll
  for (int d = 1; d < 64; d <<= 1) v += __shfl_xor(v, d, 64);
  if (t == 0) out[0] = v * (1.0f / NPTS);
}

extern "C" void kernel_launch(void* const* d_in, const int* in_sizes, int n_in,
                              void* d_out, int out_size, void* d_ws, size_t ws_size,
                              hipStream_t stream) {
  const float* x = (const float*)d_in[0];
  const float* y = (const float*)d_in[1];
  float* out = (float*)d_out;
  float* w = (float*)d_ws;

  // ws layout (float slots); total ~139*NPTS ~ 2.3 MB
  float* xs_x = w;                         // [NPTS]
  float* xs_y = w + NPTS;                  // [NPTS]
  float* pot0 = w + 2 * NPTS;              // [4][NPTS] potential ping
  float* pot1 = w + 6 * NPTS;              // [4][NPTS] potential pong
  float* pm0  = w + 10 * NPTS;             // [4][NSPLIT][NPTS]
  float* ps0  = w + 26 * NPTS;
  float* pm1  = w + 42 * NPTS;
  float* ps1  = w + 58 * NPTS;
  float* blkp = w + 74 * NPTS;             // [64] stage-1 partials
  unsigned short* xb = (unsigned short*)(w + 75 * NPTS);   // [NPTS][KD] bf16
  unsigned short* yb = (unsigned short*)(w + 107 * NPTS);  // [NPTS][KD] bf16
  float* pmb[2] = {pm0, pm1};
  float* psb[2] = {ps0, ps1};
  float* potb[2] = {pot0, pot1};

  // geomloss epsilon_schedule(p=2, diameter=20, blur=0.01, scaling=0.7)
  double eps_list[32];
  int neps = 0;
  {
    double start = 2.0 * log(20.0);
    double stop  = 2.0 * log(0.01);
    double step  = 2.0 * log(0.7);
    eps_list[neps++] = 400.0;
    int cnt = (int)ceil((stop - start) / step);  // 22
    for (int i = 0; i < cnt && neps < 30; ++i) eps_list[neps++] = exp(start + (double)i * step);
    eps_list[neps++] = 1e-4;                     // neps == 24
  }

  // dir 0: ft (rows x, cols y); dir 1: gt (rows y, cols x)
  // dir 2: f_aa (x,x); dir 3: g_bb (y,y).  qpair = paired dir whose ROWS are
  // this dir's COLS: {1,0,2,3}.
  const unsigned short* Xd[4] = {xb, yb, xb, yb};
  const unsigned short* Yd[4] = {yb, xb, xb, yb};
  const float* YSQd[4] = {xs_y, xs_x, xs_x, xs_y};   // col-side sqnorms
  const int qpair[4] = {1, 0, 2, 3};

  prep<<<dim3(32), dim3(256), 0, stream>>>(x, y, xs_x, xs_y, xb, yb);

  dim3 fgrid(NPTS / BR, NSPLIT, 4);   // 64 x 4 x 4 = 1024 blocks = 4/CU

  // eps used by launch k (k = 0 init, 1..24 loop, 25 final extrapolation)
  double ecur[26];
  ecur[0] = eps_list[0];
  for (int k = 1; k <= 24; ++k) ecur[k] = eps_list[k - 1];
  ecur[25] = eps_list[neps - 1];

  for (int k = 0; k <= 25; ++k) {
    FusedArgs fa;
    for (int d = 0; d < 4; ++d) {
      fa.X[d] = Xd[d]; fa.Y[d] = Yd[d]; fa.csq[d] = YSQd[d];
      int p = qpair[d];
      fa.pmr[d]  = pmb[(k + 1) & 1] + (size_t)p * NSPLIT * NPTS;
      fa.psr[d]  = psb[(k + 1) & 1] + (size_t)p * NSPLIT * NPTS;
      fa.potr[d] = potb[(k + 1) & 1] + (size_t)p * NPTS;
      fa.potw[d] = potb[k & 1] + (size_t)p * NPTS;
    }
    fa.pm = pmb[k & 1];
    fa.ps = psb[k & 1];
    fa.ie2 = (float)(LOG2E / ecur[k]);
    fa.elp = (k == 0) ? 0.f : (float)(ecur[k - 1] * LN2);
    fa.alpha = (k <= 1) ? 0.f : 0.5f;
    fa.beta  = (k <= 1) ? 1.f : 0.5f;
    fa.mode  = (k == 0) ? 0 : 1;
    fused_softmin<<<fgrid, dim3(NTHREADS), 0, stream>>>(fa);
  }

  final_partial<<<dim3(64), dim3(256), 0, stream>>>(
      pmb[25 & 1], psb[25 & 1], xs_x, xs_y,
      (float)(eps_list[neps - 1] * LN2), blkp);
  final_sum<<<dim3(1), dim3(64), 0, stream>>>(blkp, out);
}